// Round 7
// baseline (214.010 us; speedup 1.0000x reference)
//
#include <hip/hip_runtime.h>
#include <math.h>

#define BB   4
#define TT   4096
#define DIN  1024
#define DST  2048
#define MM   (BB*TT)     // 16384
#define CHK  32          // scan chunks per sequence
#define CLEN (TT/CHK)    // 128

typedef __bf16 bf16x8 __attribute__((ext_vector_type(8)));
typedef float  f32x4  __attribute__((ext_vector_type(4)));

__device__ __forceinline__ unsigned short f2bf(float f) {
    union { float f; unsigned u; } v; v.f = f;
    unsigned r = v.u + 0x7FFFu + ((v.u >> 16) & 1u);   // RNE
    return (unsigned short)(r >> 16);
}
__device__ __forceinline__ float bf2f(unsigned short h) {
    union { unsigned u; float f; } v; v.u = ((unsigned)h) << 16;
    return v.f;
}
__device__ __forceinline__ float sigm(float x) { return 1.f / (1.f + __expf(-x)); }

// ---------------------------------------------------------------------------
// fp32 -> bf16 conversion, 4 elems/thread
// ---------------------------------------------------------------------------
__global__ __launch_bounds__(256)
void cvt_kernel(const float* __restrict__ in, unsigned short* __restrict__ out, int n4)
{
    int i = blockIdx.x * 256 + threadIdx.x;
    if (i >= n4) return;
    float4 f = reinterpret_cast<const float4*>(in)[i];
    ushort4 o;
    o.x = f2bf(f.x); o.y = f2bf(f.y); o.z = f2bf(f.z); o.w = f2bf(f.w);
    reinterpret_cast<ushort4*>(out)[i] = o;
}

// ---------------------------------------------------------------------------
// m201-style 8-phase bf16 NT MFMA GEMM.
//   256x256 block, BK=64, 8 waves (2M x 4N), wave tile 128x64.
//   2 K-tiles per loop iteration: even tile -> buf0, odd tile -> buf1 (static).
//   8 phases/iter = 4 C-quadrants (m-half x n-half) x 2 tiles; per phase:
//     { 8-12 ds_read_b128 | stage 1 half-tile (2 gload_lds) -> s_barrier ->
//       lgkmcnt(0)+sched_barrier -> setprio(1) 16 MFMA setprio(0) -> s_barrier }
//   Counted vmcnt gates ONLY at ph4 (vmcnt 2) and ph8 (vmcnt 4) — never a
//   mid-loop full drain. Stage ledger (verified dead-region + gate coverage):
//     ph1: O.B0   ph2: O.B1   ph3: E'.A0  ph4: -      [gate vmcnt(2|0)]
//     ph5: E'.A1  ph6: E'.B0+B1  ph7: -   ph8: O'.A0+A1 [gate vmcnt(4|0)]
//   XOR swizzle col8 ^= (row&7) on stage-source AND ds_read (0-conflict).
// C[m,n] = sum_k A[m,k]*B[n,k];  A: MxK, B: NxK, both bf16 row-major.
// ---------------------------------------------------------------------------

#define RD_A(BUFB, MH)                                                         \
    _Pragma("unroll")                                                          \
    for (int m = 0; m < 4; ++m) {                                              \
        const int ar = (BUFB) + (wr * 128 + (MH) * 64 + m * 16 + fr) * 64;     \
        a0[m] = *reinterpret_cast<const bf16x8*>(&lds[ar + c0]);               \
        a1[m] = *reinterpret_cast<const bf16x8*>(&lds[ar + c1]);               \
    }

#define RD_B(BUFB, NH)                                                         \
    _Pragma("unroll")                                                          \
    for (int n = 0; n < 2; ++n) {                                              \
        const int br = (BUFB) + 16384 + (wc * 64 + (NH) * 32 + n * 16 + fr) * 64; \
        b0[n] = *reinterpret_cast<const bf16x8*>(&lds[br + c0]);               \
        b1[n] = *reinterpret_cast<const bf16x8*>(&lds[br + c1]);               \
    }

#define SYNC_IN                                                                \
    __builtin_amdgcn_s_barrier();                                              \
    asm volatile("s_waitcnt lgkmcnt(0)" ::: "memory");                         \
    __builtin_amdgcn_sched_barrier(0);                                         \
    __builtin_amdgcn_s_setprio(1);

#define MFMA16(MH, NH)                                                         \
    _Pragma("unroll")                                                          \
    for (int m = 0; m < 4; ++m)                                                \
        _Pragma("unroll")                                                      \
        for (int n = 0; n < 2; ++n) {                                          \
            acc[(MH)*4+m][(NH)*2+n] = __builtin_amdgcn_mfma_f32_16x16x32_bf16( \
                a0[m], b0[n], acc[(MH)*4+m][(NH)*2+n], 0, 0, 0);               \
            acc[(MH)*4+m][(NH)*2+n] = __builtin_amdgcn_mfma_f32_16x16x32_bf16( \
                a1[m], b1[n], acc[(MH)*4+m][(NH)*2+n], 0, 0, 0);               \
        }

#define SYNC_OUT                                                               \
    __builtin_amdgcn_s_setprio(0);                                             \
    __builtin_amdgcn_s_barrier();

template<int K, int NB, bool FUSE>
__global__ __launch_bounds__(512, 2)
void gemm_pipe(const unsigned short* __restrict__ A,
               const unsigned short* __restrict__ B,
               unsigned short* __restrict__ Obf,
               float* __restrict__ Of,
               const float* __restrict__ U,
               const float* __restrict__ Dv)
{
    constexpr int N     = NB * 256;
    constexpr int NT    = K / 64;
    constexpr int ITERS = NT / 2;
    __shared__ __align__(16) unsigned short lds[2 * 32768];   // 128 KiB

    // XCD-aware bijective swizzle (nwg % 8 == 0: 512 / 256 blocks)
    const int nwg = gridDim.x;
    const int bid = blockIdx.x;
    const int swz = (bid & 7) * (nwg >> 3) + (bid >> 3);
    const int bm = swz / NB, bn = swz % NB;

    const int tid  = threadIdx.x;
    const int lane = tid & 63;
    const int wid  = tid >> 6;          // 0..7
    const int wr   = wid >> 2;          // 0..1  (128-row band)
    const int wc   = wid & 3;           // 0..3  (64-col band)
    const int fr   = lane & 15, fq = lane >> 4;

    // --- staging: linear LDS dest, pre-swizzled global source col ---
    const int srow = tid >> 3;                                  // 0..63
    const int scol = (((tid & 7) ^ (srow & 7)) << 3);           // swizzled col
    const unsigned short* Ag = A + (size_t)(bm * 256 + srow) * K + scol;
    const unsigned short* Bg = B + (size_t)(bn * 256 + srow) * K + scol;

    // half-tile stagers: operand X, half h (rows h*128 .. h*128+127), 2 loads
    auto stA = [&](int t, int h) {
        const int buf = (t & 1) * 32768;
#pragma unroll
        for (int r = 0; r < 2; ++r)
            __builtin_amdgcn_global_load_lds(
                (const __attribute__((address_space(1))) void*)(Ag + (size_t)t * 64 + (size_t)(h * 128 + r * 64) * K),
                (__attribute__((address_space(3))) void*)(&lds[buf + h * 8192 + r * 4096 + tid * 8]),
                16, 0, 0);
    };
    auto stB = [&](int t, int h) {
        const int buf = (t & 1) * 32768;
#pragma unroll
        for (int r = 0; r < 2; ++r)
            __builtin_amdgcn_global_load_lds(
                (const __attribute__((address_space(1))) void*)(Bg + (size_t)t * 64 + (size_t)(h * 128 + r * 64) * K),
                (__attribute__((address_space(3))) void*)(&lds[buf + 16384 + h * 8192 + r * 4096 + tid * 8]),
                16, 0, 0);
    };

    // --- frag read addressing (read-side swizzle: row&7 == fr&7) ---
    const int c0 = ((fq ^ (fr & 7)) << 3);          // kk=0 col group
    const int c1 = (((4 + fq) ^ (fr & 7)) << 3);    // kk=1 col group

    f32x4 acc[8][4];
#pragma unroll
    for (int m = 0; m < 8; ++m)
#pragma unroll
        for (int n = 0; n < 4; ++n) {
            acc[m][n][0] = 0.f; acc[m][n][1] = 0.f;
            acc[m][n][2] = 0.f; acc[m][n][3] = 0.f;
        }

    bf16x8 a0[4], a1[4], b0[2], b1[2];

    // --- prologue: tile0 fully (8 loads) + tile1 A-halves (4 loads) ---
    stA(0, 0); stA(0, 1); stB(0, 0); stB(0, 1);
    stA(1, 0); stA(1, 1);
    asm volatile("s_waitcnt vmcnt(4)" ::: "memory");   // tile0 landed
    __builtin_amdgcn_s_barrier();

    for (int it = 0; it < ITERS; ++it) {
        const int  tO  = 2 * it + 1;
        const int  tE2 = 2 * it + 2, tO2 = 2 * it + 3;
        const bool sE2 = tE2 < NT, sO2 = tO2 < NT;

        // ===== ph1: (E, m0, n0) =====
        RD_A(0, 0) RD_B(0, 0)
        stB(tO, 0);
        SYNC_IN MFMA16(0, 0) SYNC_OUT

        // ===== ph2: (E, m0, n1) =====
        RD_B(0, 1)
        stB(tO, 1);
        SYNC_IN MFMA16(0, 1) SYNC_OUT

        // ===== ph3: (E, m1, n0) =====
        RD_A(0, 1) RD_B(0, 0)
        if (sE2) stA(tE2, 0);
        SYNC_IN MFMA16(1, 0) SYNC_OUT

        // ===== ph4: (E, m1, n1)  [gate] =====
        RD_B(0, 1)
        SYNC_IN MFMA16(1, 1)
        __builtin_amdgcn_s_setprio(0);
        if (sE2) asm volatile("s_waitcnt vmcnt(2)" ::: "memory");
        else     asm volatile("s_waitcnt vmcnt(0)" ::: "memory");
        __builtin_amdgcn_s_barrier();

        // ===== ph5: (O, m0, n0) =====
        RD_A(32768, 0) RD_B(32768, 0)
        if (sE2) stA(tE2, 1);
        SYNC_IN MFMA16(0, 0) SYNC_OUT

        // ===== ph6: (O, m0, n1) =====
        RD_B(32768, 1)
        if (sE2) { stB(tE2, 0); stB(tE2, 1); }
        SYNC_IN MFMA16(0, 1) SYNC_OUT

        // ===== ph7: (O, m1, n0) =====
        RD_A(32768, 1) RD_B(32768, 0)
        SYNC_IN MFMA16(1, 0) SYNC_OUT

        // ===== ph8: (O, m1, n1)  [gate] =====
        RD_B(32768, 1)
        if (sO2) { stA(tO2, 0); stA(tO2, 1); }
        SYNC_IN MFMA16(1, 1)
        __builtin_amdgcn_s_setprio(0);
        if (sO2) asm volatile("s_waitcnt vmcnt(4)" ::: "memory");
        else     asm volatile("s_waitcnt vmcnt(0)" ::: "memory");
        __builtin_amdgcn_s_barrier();
    }

    // --- epilogue.  C/D layout: col = lane&15, row = fq*4 + reg ---
    const int row0 = bm * 256 + wr * 128 + fq * 4;
    const int col0 = bn * 256 + wc * 64 + fr;
    if (FUSE) {
#pragma unroll
        for (int n = 0; n < 4; ++n) {
            const int col = col0 + n * 16;
            const float d = Dv[col];
#pragma unroll
            for (int m = 0; m < 8; ++m)
#pragma unroll
                for (int r = 0; r < 4; ++r) {
                    const size_t idx = (size_t)(row0 + m * 16 + r) * N + col;
                    Of[idx] = acc[m][n][r] + U[idx] * d;
                }
        }
    } else {
#pragma unroll
        for (int m = 0; m < 8; ++m)
#pragma unroll
            for (int r = 0; r < 4; ++r) {
                const size_t ro = (size_t)(row0 + m * 16 + r) * N;
#pragma unroll
                for (int n = 0; n < 4; ++n)
                    Obf[ro + col0 + n * 16] = f2bf(acc[m][n][r]);
            }
    }
}

// ---------------------------------------------------------------------------
// Chunked scan, 3 phases. up is bf16 [B][T][DST] = raw u_proj (unscaled).
// ---------------------------------------------------------------------------
__global__ __launch_bounds__(256)
void scan1_kernel(const unsigned short* __restrict__ up,
                  const float* __restrict__ logl,
                  float* __restrict__ fin)
{
    const int gid = blockIdx.x * 256 + threadIdx.x;   // B*CHK*(DST/2)
    const int sp  = gid & (DST / 2 - 1);
    const int bc  = gid >> 10;                         // b*CHK + c
    const int c   = bc & (CHK - 1), b = bc >> 5;
    const int s0  = sp * 2;
    const float lam0 = sigm(logl[s0]),  lam1 = sigm(logl[s0 + 1]);
    const float o0 = 1.f - lam0, o1 = 1.f - lam1;
    const ushort2* p = reinterpret_cast<const ushort2*>(
        up + ((size_t)b * TT + (size_t)c * CLEN) * DST + s0);
    float x0 = 0.f, x1 = 0.f;
    for (int t = 0; t < CLEN; ++t) {
        ushort2 v = p[(size_t)t * (DST / 2)];
        x0 = fmaf(lam0, x0, o0 * bf2f(v.x));
        x1 = fmaf(lam1, x1, o1 * bf2f(v.y));
    }
    reinterpret_cast<float2*>(fin + (size_t)bc * DST + s0)[0] = make_float2(x0, x1);
}

__global__ __launch_bounds__(256)
void scan2_kernel(float* __restrict__ fin, const float* __restrict__ logl)
{
    const int gid = blockIdx.x * 256 + threadIdx.x;   // B*DST
    const int s = gid & (DST - 1), b = gid >> 11;
    const float lam = sigm(logl[s]);
    float lamL = lam;
#pragma unroll
    for (int i = 0; i < 7; ++i) lamL *= lamL;          // lam^128
    float x = 0.f;
    float* f = fin + (size_t)b * CHK * DST + s;
#pragma unroll
    for (int c = 0; c < CHK; ++c) {
        float v = f[(size_t)c * DST];
        f[(size_t)c * DST] = x;                        // exclusive carry-in
        x = fmaf(lamL, x, v);
    }
}

__global__ __launch_bounds__(256)
void scan3_kernel(unsigned short* __restrict__ up,
                  const float* __restrict__ logl,
                  const float* __restrict__ fin)
{
    const int gid = blockIdx.x * 256 + threadIdx.x;
    const int sp  = gid & (DST / 2 - 1);
    const int bc  = gid >> 10;
    const int c   = bc & (CHK - 1), b = bc >> 5;
    const int s0  = sp * 2;
    const float lam0 = sigm(logl[s0]),  lam1 = sigm(logl[s0 + 1]);
    const float o0 = 1.f - lam0, o1 = 1.f - lam1;
    const float2 cv = reinterpret_cast<const float2*>(fin + (size_t)bc * DST + s0)[0];
    float x0 = cv.x, x1 = cv.y;
    ushort2* p = reinterpret_cast<ushort2*>(
        up + ((size_t)b * TT + (size_t)c * CLEN) * DST + s0);
    for (int t = 0; t < CLEN; ++t) {
        ushort2 v = p[(size_t)t * (DST / 2)];
        x0 = fmaf(lam0, x0, o0 * bf2f(v.x));
        x1 = fmaf(lam1, x1, o1 * bf2f(v.y));
        p[(size_t)t * (DST / 2)] = make_ushort2(f2bf(x0), f2bf(x1));
    }
}

// ---------------------------------------------------------------------------
extern "C" void kernel_launch(void* const* d_in, const int* in_sizes, int n_in,
                              void* d_out, int out_size, void* d_ws, size_t ws_size,
                              hipStream_t stream)
{
    const float* u     = (const float*)d_in[0];   // B,T,DIN
    const float* W_in  = (const float*)d_in[1];   // DST,DIN
    const float* logl  = (const float*)d_in[2];   // DST
    const float* W_out = (const float*)d_in[3];   // DIN,DST
    const float* Dv    = (const float*)d_in[4];   // DIN
    float* y = (float*)d_out;

    char* ws = (char*)d_ws;
    unsigned short* uA  = (unsigned short*)(ws);                      // 32 MiB
    unsigned short* wA  = (unsigned short*)(ws + (32ull << 20));      //  4 MiB
    unsigned short* wB  = (unsigned short*)(ws + (36ull << 20));      //  4 MiB
    unsigned short* upb = (unsigned short*)(ws + (40ull << 20));      // 64 MiB
    float*          fin = (float*)(ws + (104ull << 20));              //  1 MiB

    // fp32 -> bf16 conversions
    cvt_kernel<<<(MM * DIN / 4) / 256, 256, 0, stream>>>(u, uA, MM * DIN / 4);
    cvt_kernel<<<(DST * DIN / 4) / 256, 256, 0, stream>>>(W_in, wA, DST * DIN / 4);
    cvt_kernel<<<(DIN * DST / 4) / 256, 256, 0, stream>>>(W_out, wB, DIN * DST / 4);

    // GEMM1: u_proj (raw, unscaled) -> upb bf16
    gemm_pipe<DIN, DST / 256, false><<<(MM / 256) * (DST / 256), 512, 0, stream>>>(
        uA, wA, upb, nullptr, nullptr, nullptr);

    // chunked diagonal scan, in place on upb
    scan1_kernel<<<(BB * CHK * DST / 2) / 256, 256, 0, stream>>>(upb, logl, fin);
    scan2_kernel<<<(BB * DST) / 256, 256, 0, stream>>>(fin, logl);
    scan3_kernel<<<(BB * CHK * DST / 2) / 256, 256, 0, stream>>>(upb, logl, fin);

    // GEMM2: y = xs @ W_out^T + u*D
    gemm_pipe<DST, DIN / 256, true><<<(MM / 256) * (DIN / 256), 512, 0, stream>>>(
        upb, wB, nullptr, y, u, Dv);
}

// Round 8
// 191.501 us; speedup vs baseline: 1.1175x; 1.1175x over previous
//
#include <hip/hip_runtime.h>
#include <math.h>

#define BB   4
#define TT   4096
#define DIN  1024
#define DST  2048
#define MM   (BB*TT)     // 16384
#define CHK  32          // scan chunks per sequence
#define CLEN (TT/CHK)    // 128

typedef __bf16 bf16x8 __attribute__((ext_vector_type(8)));
typedef float  f32x4  __attribute__((ext_vector_type(4)));

__device__ __forceinline__ unsigned short f2bf(float f) {
    union { float f; unsigned u; } v; v.f = f;
    unsigned r = v.u + 0x7FFFu + ((v.u >> 16) & 1u);   // RNE
    return (unsigned short)(r >> 16);
}
__device__ __forceinline__ float bf2f(unsigned short h) {
    union { unsigned u; float f; } v; v.u = ((unsigned)h) << 16;
    return v.f;
}
__device__ __forceinline__ float sigm(float x) { return 1.f / (1.f + __expf(-x)); }

// ---------------------------------------------------------------------------
// fused fp32 -> bf16 conversion of u, W_in, W_out in ONE launch.
// flat float4 index space: [0, N_U4) -> u, [N_U4, N_U4+N_W4) -> W_in,
// [N_U4+N_W4, N_U4+2*N_W4) -> W_out.  (N_W4 identical for both weights.)
// ---------------------------------------------------------------------------
#define N_U4 (MM * DIN / 4)          // 4,194,304
#define N_W4 (DST * DIN / 4)         //   524,288

__global__ __launch_bounds__(256)
void cvt_all_kernel(const float* __restrict__ u,
                    const float* __restrict__ W_in,
                    const float* __restrict__ W_out,
                    unsigned short* __restrict__ uA,
                    unsigned short* __restrict__ wA,
                    unsigned short* __restrict__ wB)
{
    int i = blockIdx.x * 256 + threadIdx.x;
    const float* src; unsigned short* dst; int idx;
    if (i < N_U4)                { src = u;     dst = uA; idx = i; }
    else if (i < N_U4 + N_W4)    { src = W_in;  dst = wA; idx = i - N_U4; }
    else                         { src = W_out; dst = wB; idx = i - N_U4 - N_W4; }
    float4 f = reinterpret_cast<const float4*>(src)[idx];
    ushort4 o;
    o.x = f2bf(f.x); o.y = f2bf(f.y); o.z = f2bf(f.z); o.w = f2bf(f.w);
    reinterpret_cast<ushort4*>(dst)[idx] = o;
}

// ---------------------------------------------------------------------------
// Pipelined bf16 NT MFMA GEMM (round-5 structure — best measured: 86.9 µs).
//   256x256 block, BK=64, 8 waves (2M x 4N), wave tile 128x64.
//   2-deep LDS double buffer (2 x 64 KiB = 128 KiB).
//   8 staging loads/thread/K-tile; prologue stages tiles 0,1;
//   steady-state s_waitcnt vmcnt(8) (next tile's 8 loads stay in flight).
//   Per K-tile: bar1 -> 24 ds_reads (kk0 | kk1 regions) -> lgkm(12) ->
//   32 MFMA(kk0) -> lgkm(0) -> bar2 -> stage(t+2) -> 32 MFMA(kk1).
//   XOR swizzle col8 ^= (row&7) on stage-source AND ds_read (0-conflict).
// C[m,n] = sum_k A[m,k]*B[n,k];  A: MxK, B: NxK, both bf16 row-major.
// FUSE=false: Obf = bf16(acc)                      (GEMM1)
// FUSE=true : Of  = acc + bf2f(Ubf)*Dv[col]        (GEMM2, U read as bf16)
// ---------------------------------------------------------------------------
template<int K, int NB, bool FUSE>
__global__ __launch_bounds__(512, 2)
void gemm_pipe(const unsigned short* __restrict__ A,
               const unsigned short* __restrict__ B,
               unsigned short* __restrict__ Obf,
               float* __restrict__ Of,
               const unsigned short* __restrict__ Ubf,
               const float* __restrict__ Dv)
{
    constexpr int N  = NB * 256;
    constexpr int NT = K / 64;
    __shared__ __align__(16) unsigned short lds[2 * 32768];   // 128 KiB

    // XCD-aware bijective swizzle (nwg % 8 == 0: 512 / 256 blocks)
    const int nwg = gridDim.x;
    const int bid = blockIdx.x;
    const int swz = (bid & 7) * (nwg >> 3) + (bid >> 3);
    const int bm = swz / NB, bn = swz % NB;

    const int tid  = threadIdx.x;
    const int lane = tid & 63;
    const int wid  = tid >> 6;          // 0..7
    const int wr   = wid >> 2;          // 0..1  (128-row band)
    const int wc   = wid & 3;           // 0..3  (64-col band)
    const int fr   = lane & 15, fq = lane >> 4;

    // --- staging: linear LDS dest, pre-swizzled global source col ---
    const int srow = tid >> 3;                                  // 0..63
    const int scol = (((tid & 7) ^ (srow & 7)) << 3);           // swizzled col
    const unsigned short* Ag = A + (size_t)(bm * 256 + srow) * K + scol;
    const unsigned short* Bg = B + (size_t)(bn * 256 + srow) * K + scol;

    auto stage = [&](int t) {          // 8 loads: A rounds 0-3, B rounds 0-3
        const int buf = (t & 1) * 32768;
        const size_t kof = (size_t)t * 64;
#pragma unroll
        for (int r = 0; r < 4; ++r)
            __builtin_amdgcn_global_load_lds(
                (const __attribute__((address_space(1))) void*)(Ag + kof + (size_t)r * 64 * K),
                (__attribute__((address_space(3))) void*)(&lds[buf + r * 4096 + tid * 8]),
                16, 0, 0);
#pragma unroll
        for (int r = 0; r < 4; ++r)
            __builtin_amdgcn_global_load_lds(
                (const __attribute__((address_space(1))) void*)(Bg + kof + (size_t)r * 64 * K),
                (__attribute__((address_space(3))) void*)(&lds[buf + 16384 + r * 4096 + tid * 8]),
                16, 0, 0);
    };

    // --- frag read addressing (read-side swizzle: row&7 == fr&7) ---
    const int c0 = ((fq ^ (fr & 7)) << 3);          // kk=0 col group
    const int c1 = (((4 + fq) ^ (fr & 7)) << 3);    // kk=1 col group
    const int aBase = (wr * 128 + fr) * 64;                 // + m*1024
    const int bBase = 16384 + (wc * 64 + fr) * 64;          // + n*1024

    f32x4 accA[4][4], accB[4][4];   // m 0..3 / m 4..7
#pragma unroll
    for (int m = 0; m < 4; ++m)
#pragma unroll
        for (int n = 0; n < 4; ++n) {
            accA[m][n][0] = 0.f; accA[m][n][1] = 0.f; accA[m][n][2] = 0.f; accA[m][n][3] = 0.f;
            accB[m][n][0] = 0.f; accB[m][n][1] = 0.f; accB[m][n][2] = 0.f; accB[m][n][3] = 0.f;
        }

    // --- prologue: stage tiles 0 and 1 ---
    stage(0);
    stage(1);

    for (int t = 0; t < NT; ++t) {
        // counted vmcnt: tile t's 8 landed; tile t+1's 8 stay in flight
        if (t < NT - 1) asm volatile("s_waitcnt vmcnt(8)" ::: "memory");
        else            asm volatile("s_waitcnt vmcnt(0)" ::: "memory");
        __builtin_amdgcn_s_barrier();                 // bar1: tile t visible
        __builtin_amdgcn_sched_barrier(0);

        const int bufb = (t & 1) * 32768;

        bf16x8 a0v[8], b0v[4], a1v[8], b1v[4];
        // region 1: kk0 frags (12 ds_reads)
#pragma unroll
        for (int m = 0; m < 8; ++m)
            a0v[m] = *reinterpret_cast<const bf16x8*>(&lds[bufb + aBase + m * 1024 + c0]);
#pragma unroll
        for (int n = 0; n < 4; ++n)
            b0v[n] = *reinterpret_cast<const bf16x8*>(&lds[bufb + bBase + n * 1024 + c0]);
        __builtin_amdgcn_sched_barrier(0);
        // region 2: kk1 frags (12 ds_reads) — land under kk0 MFMAs
#pragma unroll
        for (int m = 0; m < 8; ++m)
            a1v[m] = *reinterpret_cast<const bf16x8*>(&lds[bufb + aBase + m * 1024 + c1]);
#pragma unroll
        for (int n = 0; n < 4; ++n)
            b1v[n] = *reinterpret_cast<const bf16x8*>(&lds[bufb + bBase + n * 1024 + c1]);
        asm volatile("s_waitcnt lgkmcnt(12)" ::: "memory");   // kk0's 12 landed
        __builtin_amdgcn_sched_barrier(0);

        __builtin_amdgcn_s_setprio(1);
#pragma unroll
        for (int m = 0; m < 4; ++m)
#pragma unroll
            for (int n = 0; n < 4; ++n) {
                accA[m][n] = __builtin_amdgcn_mfma_f32_16x16x32_bf16(
                    a0v[m], b0v[n], accA[m][n], 0, 0, 0);
                accB[m][n] = __builtin_amdgcn_mfma_f32_16x16x32_bf16(
                    a0v[4 + m], b0v[n], accB[m][n], 0, 0, 0);
            }
        __builtin_amdgcn_s_setprio(0);

        asm volatile("s_waitcnt lgkmcnt(0)" ::: "memory");    // kk1 frags landed
        __builtin_amdgcn_sched_barrier(0);
        __builtin_amdgcn_s_barrier();                 // bar2: all reads of buf done
        if (t + 2 < NT) stage(t + 2);                 // safe to overwrite buf

        __builtin_amdgcn_s_setprio(1);
#pragma unroll
        for (int m = 0; m < 4; ++m)
#pragma unroll
            for (int n = 0; n < 4; ++n) {
                accA[m][n] = __builtin_amdgcn_mfma_f32_16x16x32_bf16(
                    a1v[m], b1v[n], accA[m][n], 0, 0, 0);
                accB[m][n] = __builtin_amdgcn_mfma_f32_16x16x32_bf16(
                    a1v[4 + m], b1v[n], accB[m][n], 0, 0, 0);
            }
        __builtin_amdgcn_s_setprio(0);
    }

    // --- epilogue.  C/D layout: col = lane&15, row = fq*4 + reg ---
    const int row0 = bm * 256 + wr * 128 + fq * 4;
    const int col0 = bn * 256 + wc * 64 + fr;
    if (FUSE) {
#pragma unroll
        for (int n = 0; n < 4; ++n) {
            const int col = col0 + n * 16;
            const float d = Dv[col];
#pragma unroll
            for (int m = 0; m < 4; ++m)
#pragma unroll
                for (int r = 0; r < 4; ++r) {
                    const size_t ia = (size_t)(row0 + m * 16 + r) * N + col;
                    const size_t ib = (size_t)(row0 + 64 + m * 16 + r) * N + col;
                    Of[ia] = accA[m][n][r] + bf2f(Ubf[ia]) * d;
                    Of[ib] = accB[m][n][r] + bf2f(Ubf[ib]) * d;
                }
        }
    } else {
#pragma unroll
        for (int m = 0; m < 4; ++m)
#pragma unroll
            for (int r = 0; r < 4; ++r) {
                const size_t ra = (size_t)(row0 + m * 16 + r) * N;
                const size_t rb = (size_t)(row0 + 64 + m * 16 + r) * N;
#pragma unroll
                for (int n = 0; n < 4; ++n) {
                    Obf[ra + col0 + n * 16] = f2bf(accA[m][n][r]);
                    Obf[rb + col0 + n * 16] = f2bf(accB[m][n][r]);
                }
            }
    }
}

// ---------------------------------------------------------------------------
// Chunked scan, 3 phases. up is bf16 [B][T][DST] = raw u_proj (unscaled).
// ---------------------------------------------------------------------------
__global__ __launch_bounds__(256)
void scan1_kernel(const unsigned short* __restrict__ up,
                  const float* __restrict__ logl,
                  float* __restrict__ fin)
{
    const int gid = blockIdx.x * 256 + threadIdx.x;   // B*CHK*(DST/2)
    const int sp  = gid & (DST / 2 - 1);
    const int bc  = gid >> 10;                         // b*CHK + c
    const int c   = bc & (CHK - 1), b = bc >> 5;
    const int s0  = sp * 2;
    const float lam0 = sigm(logl[s0]),  lam1 = sigm(logl[s0 + 1]);
    const float o0 = 1.f - lam0, o1 = 1.f - lam1;
    const ushort2* p = reinterpret_cast<const ushort2*>(
        up + ((size_t)b * TT + (size_t)c * CLEN) * DST + s0);
    float x0 = 0.f, x1 = 0.f;
    for (int t = 0; t < CLEN; ++t) {
        ushort2 v = p[(size_t)t * (DST / 2)];
        x0 = fmaf(lam0, x0, o0 * bf2f(v.x));
        x1 = fmaf(lam1, x1, o1 * bf2f(v.y));
    }
    reinterpret_cast<float2*>(fin + (size_t)bc * DST + s0)[0] = make_float2(x0, x1);
}

__global__ __launch_bounds__(256)
void scan2_kernel(float* __restrict__ fin, const float* __restrict__ logl)
{
    const int gid = blockIdx.x * 256 + threadIdx.x;   // B*DST
    const int s = gid & (DST - 1), b = gid >> 11;
    const float lam = sigm(logl[s]);
    float lamL = lam;
#pragma unroll
    for (int i = 0; i < 7; ++i) lamL *= lamL;          // lam^128
    float x = 0.f;
    float* f = fin + (size_t)b * CHK * DST + s;
#pragma unroll
    for (int c = 0; c < CHK; ++c) {
        float v = f[(size_t)c * DST];
        f[(size_t)c * DST] = x;                        // exclusive carry-in
        x = fmaf(lamL, x, v);
    }
}

__global__ __launch_bounds__(256)
void scan3_kernel(unsigned short* __restrict__ up,
                  const float* __restrict__ logl,
                  const float* __restrict__ fin)
{
    const int gid = blockIdx.x * 256 + threadIdx.x;
    const int sp  = gid & (DST / 2 - 1);
    const int bc  = gid >> 10;
    const int c   = bc & (CHK - 1), b = bc >> 5;
    const int s0  = sp * 2;
    const float lam0 = sigm(logl[s0]),  lam1 = sigm(logl[s0 + 1]);
    const float o0 = 1.f - lam0, o1 = 1.f - lam1;
    const float2 cv = reinterpret_cast<const float2*>(fin + (size_t)bc * DST + s0)[0];
    float x0 = cv.x, x1 = cv.y;
    ushort2* p = reinterpret_cast<ushort2*>(
        up + ((size_t)b * TT + (size_t)c * CLEN) * DST + s0);
    for (int t = 0; t < CLEN; ++t) {
        ushort2 v = p[(size_t)t * (DST / 2)];
        x0 = fmaf(lam0, x0, o0 * bf2f(v.x));
        x1 = fmaf(lam1, x1, o1 * bf2f(v.y));
        p[(size_t)t * (DST / 2)] = make_ushort2(f2bf(x0), f2bf(x1));
    }
}

// ---------------------------------------------------------------------------
extern "C" void kernel_launch(void* const* d_in, const int* in_sizes, int n_in,
                              void* d_out, int out_size, void* d_ws, size_t ws_size,
                              hipStream_t stream)
{
    const float* u     = (const float*)d_in[0];   // B,T,DIN
    const float* W_in  = (const float*)d_in[1];   // DST,DIN
    const float* logl  = (const float*)d_in[2];   // DST
    const float* W_out = (const float*)d_in[3];   // DIN,DST
    const float* Dv    = (const float*)d_in[4];   // DIN
    float* y = (float*)d_out;

    char* ws = (char*)d_ws;
    unsigned short* uA  = (unsigned short*)(ws);                      // 32 MiB
    unsigned short* wA  = (unsigned short*)(ws + (32ull << 20));      //  4 MiB
    unsigned short* wB  = (unsigned short*)(ws + (36ull << 20));      //  4 MiB
    unsigned short* upb = (unsigned short*)(ws + (40ull << 20));      // 64 MiB
    float*          fin = (float*)(ws + (104ull << 20));              //  1 MiB

    // fused fp32 -> bf16 conversions (one launch)
    cvt_all_kernel<<<(N_U4 + 2 * N_W4) / 256, 256, 0, stream>>>(
        u, W_in, W_out, uA, wA, wB);

    // GEMM1: u_proj (raw, unscaled) -> upb bf16
    gemm_pipe<DIN, DST / 256, false><<<(MM / 256) * (DST / 256), 512, 0, stream>>>(
        uA, wA, upb, nullptr, nullptr, nullptr);

    // chunked diagonal scan, in place on upb
    scan1_kernel<<<(BB * CHK * DST / 2) / 256, 256, 0, stream>>>(upb, logl, fin);
    scan2_kernel<<<(BB * DST) / 256, 256, 0, stream>>>(fin, logl);
    scan3_kernel<<<(BB * CHK * DST / 2) / 256, 256, 0, stream>>>(upb, logl, fin);

    // GEMM2: y = xs @ W_out^T + uA*D   (U read as bf16 — saves 32 MiB fetch)
    gemm_pipe<DST, DIN / 256, true><<<(MM / 256) * (DIN / 256), 512, 0, stream>>>(
        upb, wB, nullptr, y, uA, Dv);
}